// Round 6
// baseline (411.507 us; speedup 1.0000x reference)
//
#include <hip/hip_runtime.h>

// ObjectMeanDirectAttention — Round 6: single-pass x. Scatter reads recycled fragment
// registers via a per-wave LDS transpose tile instead of re-reading x from HBM.
// - R5 structure kept: 64 nodes/wave, swapped-operand MFMA (zero cross-lane MLP), merged launch.
// - Per q-group: x-tile (f32, already in regs for MFMA) is scaled by a[n] and ds_written
//   to a 16x68 per-wave LDS tile; scatter accumulates with 16 ds_read_b32 (2-way banks = free).
// - HBM traffic: one streaming pass of x1+x2 (512 MB) + batch + num atomics.

#define NGRAPHS 4096
constexpr int LDP = 68;    // f32 LDS stride, final MLP
constexpr int LDU = 132;   // f32 LDS stride, 128-wide u tile
constexpr int LDX = 68;    // f32 LDS stride, scatter transpose tile

typedef short bf16x8 __attribute__((ext_vector_type(8)));
typedef float f32x4 __attribute__((ext_vector_type(4)));

union BF8 { bf16x8 v; unsigned u[4]; };

__device__ __forceinline__ unsigned short f2bf(float f) {
    unsigned u = __float_as_uint(f);
    return (unsigned short)((u + 0x7FFFu + ((u >> 16) & 1u)) >> 16);  // RNE
}

__device__ __forceinline__ unsigned cvt_pk_bf16(float lo, float hi) {
    unsigned r;
    asm("v_cvt_pk_bf16_f32 %0, %1, %2" : "=v"(r) : "v"(lo), "v"(hi));
    return r;
}

__device__ __forceinline__ int lower_bound_i(const int* __restrict__ arr, int n, int v) {
    int lo = 0, hi = n;
    while (lo < hi) {
        int mid = (lo + hi) >> 1;
        if (arr[mid] < v) lo = mid + 1; else hi = mid;
    }
    return lo;
}

// one-shot weight prep:
//   w1p[r*64+k] = bf16(W1[k][pi(r)]) with pi(16ct+4kb+reg) = 32*(ct>>1)+8kb+4*(ct&1)+reg
//   w2t[r*64+k] = bf16(W2[k][r])
__global__ __launch_bounds__(256)
void convert_weights_kernel(const float* __restrict__ W1, const float* __restrict__ W2,
                            unsigned short* __restrict__ w1p, unsigned short* __restrict__ w2t) {
    int e = blockIdx.x * 256 + threadIdx.x;     // 0..4095
    int r = e >> 6, k = e & 63;
    int ct = r >> 4, kb = (r >> 2) & 3, reg = r & 3;
    int pi = 32 * (ct >> 1) + 8 * kb + 4 * (ct & 1) + reg;
    w1p[e] = f2bf(W1[k * 64 + pi]);
    w2t[e] = f2bf(W2[k * 64 + r]);
}

// ---------------- attention MLP + weighted scatter (both inputs, one launch) ----------------
__global__ __launch_bounds__(512, 4)
void attn_scatter_mfma(const float* __restrict__ x1, const int* __restrict__ batch1, int N1, int nblk1,
                       const float* __restrict__ x2, const int* __restrict__ batch2, int N2,
                       const unsigned short* __restrict__ w1p, const unsigned short* __restrict__ w2t,
                       const float* __restrict__ b1, const float* __restrict__ b2,
                       const float* __restrict__ W3, const float* __restrict__ b3,
                       float* __restrict__ num) {
    __shared__ float Xs[8][16 * LDX];   // per-wave 16-node x*a transpose tile (wave-private)

    const float* x; const int* batch; int N, col_off, blk;
    if ((int)blockIdx.x < nblk1) { x = x1; batch = batch1; N = N1; col_off = 0;  blk = blockIdx.x; }
    else                         { x = x2; batch = batch2; N = N2; col_off = 64; blk = blockIdx.x - nblk1; }

    const int t = threadIdx.x;
    const int w = t >> 6, l = t & 63;
    const int jj = l & 15, kb = l >> 4;
    const int base = blk * 512 + w * 64;          // this wave's 64 nodes
    if (base >= N) return;                        // fully-dead wave (tail block only)

    // ---- per-wave coefficient loads ----
    f32x4 b1q[4];
    b1q[0] = *(const f32x4*)&b1[8 * kb];
    b1q[1] = *(const f32x4*)&b1[8 * kb + 4];
    b1q[2] = *(const f32x4*)&b1[32 + 8 * kb];
    b1q[3] = *(const f32x4*)&b1[32 + 8 * kb + 4];
    f32x4 b2q[4];
    float4 w3q[4];
#pragma unroll
    for (int ct = 0; ct < 4; ct++) {
        b2q[ct] = *(const f32x4*)&b2[ct * 16 + 4 * kb];
        w3q[ct] = *(const float4*)&W3[ct * 16 + 4 * kb];
    }
    const float b3v = b3[0];

    // ---- per-wave weight fragments (bf16, L1-resident) ----
    bf16x8 w1f[8], w2f[8];
#pragma unroll
    for (int ct = 0; ct < 4; ct++) {
        const int wrow = (ct * 16 + jj) * 64 + kb * 8;
        w1f[2 * ct]     = *(const bf16x8*)&w1p[wrow];
        w1f[2 * ct + 1] = *(const bf16x8*)&w1p[wrow + 32];
        w2f[2 * ct]     = *(const bf16x8*)&w2t[wrow];
        w2f[2 * ct + 1] = *(const bf16x8*)&w2t[wrow + 32];
    }

    float* Xw = Xs[w];
    float accv = 0.f;
    int gcur = -1;

    // ---- 4 sequential 16-node groups: load -> MLP -> scale -> LDS transpose -> scatter ----
#pragma unroll
    for (int q = 0; q < 4; ++q) {
        const int row = base + q * 16 + jj;
        // X fragment: lane (jj,kb) holds node jj's feats kb*8..+7 and 32+kb*8..+7
        float4 v0 = make_float4(0.f, 0.f, 0.f, 0.f), v1 = v0, v2 = v0, v3 = v0;
        if (row < N) {
            const float* xr = x + (size_t)row * 64;
            v0 = *(const float4*)&xr[kb * 8];
            v1 = *(const float4*)&xr[kb * 8 + 4];
            v2 = *(const float4*)&xr[32 + kb * 8];
            v3 = *(const float4*)&xr[32 + kb * 8 + 4];
        }
        const int gb = batch[row < N ? row : (N - 1)];

        BF8 xb0, xb1;
        xb0.u[0] = cvt_pk_bf16(v0.x, v0.y); xb0.u[1] = cvt_pk_bf16(v0.z, v0.w);
        xb0.u[2] = cvt_pk_bf16(v1.x, v1.y); xb0.u[3] = cvt_pk_bf16(v1.z, v1.w);
        xb1.u[0] = cvt_pk_bf16(v2.x, v2.y); xb1.u[1] = cvt_pk_bf16(v2.z, v2.w);
        xb1.u[2] = cvt_pk_bf16(v3.x, v3.y); xb1.u[3] = cvt_pk_bf16(v3.z, v3.w);

        // layer 1 (swapped): lane holds H1pre[node jj][pi(ct,kb,reg)]
        unsigned ph[8];
#pragma unroll
        for (int ct = 0; ct < 4; ++ct) {
            f32x4 acc = b1q[ct];
            acc = __builtin_amdgcn_mfma_f32_16x16x32_bf16(w1f[2 * ct],     xb0.v, acc, 0, 0, 0);
            acc = __builtin_amdgcn_mfma_f32_16x16x32_bf16(w1f[2 * ct + 1], xb1.v, acc, 0, 0, 0);
            ph[2 * ct]     = cvt_pk_bf16(fmaxf(acc[0], 0.f), fmaxf(acc[1], 0.f));
            ph[2 * ct + 1] = cvt_pk_bf16(fmaxf(acc[2], 0.f), fmaxf(acc[3], 0.f));
        }
        BF8 bh0, bh1;
        bh0.u[0] = ph[0]; bh0.u[1] = ph[1]; bh0.u[2] = ph[2]; bh0.u[3] = ph[3];
        bh1.u[0] = ph[4]; bh1.u[1] = ph[5]; bh1.u[2] = ph[6]; bh1.u[3] = ph[7];

        // layer 2+3 (swapped): lane holds H2pre[node jj][16ct+4kb+reg]
        float p = 0.f;
#pragma unroll
        for (int ct = 0; ct < 4; ++ct) {
            f32x4 acc = b2q[ct];
            acc = __builtin_amdgcn_mfma_f32_16x16x32_bf16(w2f[2 * ct],     bh0.v, acc, 0, 0, 0);
            acc = __builtin_amdgcn_mfma_f32_16x16x32_bf16(w2f[2 * ct + 1], bh1.v, acc, 0, 0, 0);
            p += fmaxf(acc[0], 0.f) * w3q[ct].x + fmaxf(acc[1], 0.f) * w3q[ct].y
               + fmaxf(acc[2], 0.f) * w3q[ct].z + fmaxf(acc[3], 0.f) * w3q[ct].w;
        }
        // reduce the 4 kb partials of node jj -> every lane holds a[its node jj]
        p += __shfl_xor(p, 16);
        p += __shfl_xor(p, 32);
        const float a = p + b3v;

        // scale x by a and transpose through wave-private LDS (no HBM re-read)
        float4 s0 = make_float4(v0.x * a, v0.y * a, v0.z * a, v0.w * a);
        float4 s1 = make_float4(v1.x * a, v1.y * a, v1.z * a, v1.w * a);
        float4 s2 = make_float4(v2.x * a, v2.y * a, v2.z * a, v2.w * a);
        float4 s3 = make_float4(v3.x * a, v3.y * a, v3.z * a, v3.w * a);
        *(float4*)&Xw[jj * LDX + kb * 8]          = s0;
        *(float4*)&Xw[jj * LDX + kb * 8 + 4]      = s1;
        *(float4*)&Xw[jj * LDX + 32 + kb * 8]     = s2;
        *(float4*)&Xw[jj * LDX + 32 + kb * 8 + 4] = s3;
        // same-wave RAW: compiler inserts lgkmcnt wait; tile is wave-private (no barrier)

        // scatter: accumulate weighted rows, flush at graph boundaries (wave-uniform, rare)
        if (gcur < 0) gcur = __shfl(gb, 0);
#pragma unroll
        for (int i = 0; i < 16; ++i) {
            const int n = base + q * 16 + i;
            if (n < N) {                                   // wave-uniform
                const int g = __shfl(gb, i);               // batch[n]
                if (g != gcur) {
                    atomicAdd(&num[(size_t)gcur * 128 + col_off + l], accv);
                    accv = 0.f;
                    gcur = g;
                }
                accv += Xw[i * LDX + l];                   // x[n][l] * a[n]
            }
        }
    }
    atomicAdd(&num[(size_t)gcur * 128 + col_off + l], accv);
}

// ---------------- final MLP (f32, unchanged: negligible time) ----------------
template<int K, int LDAa, int LDBb>
__device__ __forceinline__ void tile_gemm(const float* __restrict__ As,
                                          const float* __restrict__ Bs,
                                          float acc[4][4], int n0, int j0) {
#pragma unroll 4
    for (int k0 = 0; k0 < K; k0 += 4) {
        float4 a[4], wv[4];
#pragma unroll
        for (int i = 0; i < 4; i++) a[i] = *(const float4*)&As[(n0 + i) * LDAa + k0];
#pragma unroll
        for (int kk = 0; kk < 4; kk++) wv[kk] = *(const float4*)&Bs[(k0 + kk) * LDBb + j0];
#pragma unroll
        for (int i = 0; i < 4; i++) {
            const float av0 = a[i].x, av1 = a[i].y, av2 = a[i].z, av3 = a[i].w;
            acc[i][0] += av0 * wv[0].x; acc[i][1] += av0 * wv[0].y; acc[i][2] += av0 * wv[0].z; acc[i][3] += av0 * wv[0].w;
            acc[i][0] += av1 * wv[1].x; acc[i][1] += av1 * wv[1].y; acc[i][2] += av1 * wv[1].z; acc[i][3] += av1 * wv[1].w;
            acc[i][0] += av2 * wv[2].x; acc[i][1] += av2 * wv[2].y; acc[i][2] += av2 * wv[2].z; acc[i][3] += av2 * wv[2].w;
            acc[i][0] += av3 * wv[3].x; acc[i][1] += av3 * wv[3].y; acc[i][2] += av3 * wv[3].z; acc[i][3] += av3 * wv[3].w;
        }
    }
}

__global__ __launch_bounds__(256)
void final_mlp_kernel(const float* __restrict__ num,
                      const int* __restrict__ batch1, int N1,
                      const int* __restrict__ batch2, int N2,
                      const float* __restrict__ W1, const float* __restrict__ b1,  // [128][64]
                      const float* __restrict__ W2, const float* __restrict__ b2,  // [64][64]
                      const float* __restrict__ W3, const float* __restrict__ b3,  // [64][64]
                      float* __restrict__ out) {
    __shared__ float Us[64 * LDU];
    __shared__ float W1s[128 * LDP];
    __shared__ float W2s[64 * LDP];
    __shared__ float W3s[64 * LDP];
    __shared__ float Hs[64 * LDP];
    __shared__ float inv1[64], inv2[64];

    const int t = threadIdx.x;
    const int rowbase = blockIdx.x * 64;

    if (t < 64) {
        int g = rowbase + t;
        int c = lower_bound_i(batch1, N1, g + 1) - lower_bound_i(batch1, N1, g);
        inv1[t] = 1.0f / (float)max(c, 1);
    } else if (t < 128) {
        int g = rowbase + (t - 64);
        int c = lower_bound_i(batch2, N2, g + 1) - lower_bound_i(batch2, N2, g);
        inv2[t - 64] = 1.0f / (float)max(c, 1);
    }

    {
        const float4* W1v = (const float4*)W1;
#pragma unroll
        for (int r = 0; r < 8; r++) {
            int e4 = t + 256 * r;
            int e = e4 * 4;
            int k = e / 64, j = e % 64;
            *(float4*)&W1s[k * LDP + j] = W1v[e4];
        }
        const float4* W2v = (const float4*)W2;
        const float4* W3v = (const float4*)W3;
#pragma unroll
        for (int r = 0; r < 4; r++) {
            int e4 = t + 256 * r;
            int e = e4 * 4;
            int k = e / 64, j = e % 64;
            *(float4*)&W2s[k * LDP + j] = W2v[e4];
            *(float4*)&W3s[k * LDP + j] = W3v[e4];
        }
    }
    __syncthreads();

    {
        const float4* nv = (const float4*)(num + (size_t)rowbase * 128);
#pragma unroll
        for (int r = 0; r < 8; r++) {
            int e4 = t + 256 * r;
            int e = e4 * 4;
            int row = e / 128, col = e % 128;
            float4 v = nv[e4];
            float s = (col < 64) ? inv1[row] : inv2[row];
            v.x *= s; v.y *= s; v.z *= s; v.w *= s;
            *(float4*)&Us[row * LDU + col] = v;
        }
    }
    __syncthreads();

    const int fg = t & 15, ng = t >> 4;
    const int j0 = fg * 4, n0 = ng * 4;

    float acc[4][4];
#pragma unroll
    for (int i = 0; i < 4; i++) { acc[i][0] = 0.f; acc[i][1] = 0.f; acc[i][2] = 0.f; acc[i][3] = 0.f; }
    tile_gemm<128, LDU, LDP>(Us, W1s, acc, n0, j0);
    {
        float4 bb = *(const float4*)&b1[j0];
#pragma unroll
        for (int i = 0; i < 4; i++) {
            float4 hv;
            hv.x = fmaxf(acc[i][0] + bb.x, 0.f);
            hv.y = fmaxf(acc[i][1] + bb.y, 0.f);
            hv.z = fmaxf(acc[i][2] + bb.z, 0.f);
            hv.w = fmaxf(acc[i][3] + bb.w, 0.f);
            *(float4*)&Hs[(n0 + i) * LDP + j0] = hv;
        }
    }
    __syncthreads();

#pragma unroll
    for (int i = 0; i < 4; i++) { acc[i][0] = 0.f; acc[i][1] = 0.f; acc[i][2] = 0.f; acc[i][3] = 0.f; }
    tile_gemm<64, LDP, LDP>(Hs, W2s, acc, n0, j0);
    {
        float4 bb = *(const float4*)&b2[j0];
#pragma unroll
        for (int i = 0; i < 4; i++) {
            float4 hv;
            hv.x = fmaxf(acc[i][0] + bb.x, 0.f);
            hv.y = fmaxf(acc[i][1] + bb.y, 0.f);
            hv.z = fmaxf(acc[i][2] + bb.z, 0.f);
            hv.w = fmaxf(acc[i][3] + bb.w, 0.f);
            *(float4*)&Us[(n0 + i) * LDU + j0] = hv;
        }
    }
    __syncthreads();

#pragma unroll
    for (int i = 0; i < 4; i++) { acc[i][0] = 0.f; acc[i][1] = 0.f; acc[i][2] = 0.f; acc[i][3] = 0.f; }
    tile_gemm<64, LDU, LDP>(Us, W3s, acc, n0, j0);
    {
        float4 bb = *(const float4*)&b3[j0];
#pragma unroll
        for (int i = 0; i < 4; i++) {
            float4 ov;
            ov.x = acc[i][0] + bb.x;
            ov.y = acc[i][1] + bb.y;
            ov.z = acc[i][2] + bb.z;
            ov.w = acc[i][3] + bb.w;
            *(float4*)&out[(size_t)(rowbase + n0 + i) * 64 + j0] = ov;
        }
    }
}

extern "C" void kernel_launch(void* const* d_in, const int* in_sizes, int n_in,
                              void* d_out, int out_size, void* d_ws, size_t ws_size,
                              hipStream_t stream) {
    const float* x1     = (const float*)d_in[0];
    const int*   batch1 = (const int*)d_in[1];
    const float* x2     = (const float*)d_in[2];
    const int*   batch2 = (const int*)d_in[3];
    const float* aW1    = (const float*)d_in[4];
    const float* ab1    = (const float*)d_in[5];
    const float* aW2    = (const float*)d_in[6];
    const float* ab2    = (const float*)d_in[7];
    const float* aW3    = (const float*)d_in[8];
    const float* ab3    = (const float*)d_in[9];
    const float* fW1    = (const float*)d_in[10];
    const float* fb1    = (const float*)d_in[11];
    const float* fW2    = (const float*)d_in[12];
    const float* fb2    = (const float*)d_in[13];
    const float* fW3    = (const float*)d_in[14];
    const float* fb3    = (const float*)d_in[15];

    const int N1 = in_sizes[0] / 64;
    const int N2 = in_sizes[2] / 64;

    // ws layout: [w1p bf16 8KB][w2t bf16 8KB][num f32 4096x128 = 2MB]
    unsigned short* w1p = (unsigned short*)d_ws;
    unsigned short* w2t = w1p + 64 * 64;
    float* num = (float*)((char*)d_ws + 16384);

    convert_weights_kernel<<<dim3(16), dim3(256), 0, stream>>>(aW1, aW2, w1p, w2t);
    hipMemsetAsync(num, 0, (size_t)NGRAPHS * 128 * sizeof(float), stream);

    const int nblk1 = (N1 + 511) / 512;
    const int nblk2 = (N2 + 511) / 512;
    attn_scatter_mfma<<<dim3(nblk1 + nblk2), dim3(512), 0, stream>>>(
        x1, batch1, N1, nblk1, x2, batch2, N2,
        w1p, w2t, ab1, ab2, aW3, ab3, num);
    final_mlp_kernel<<<dim3(NGRAPHS / 64), dim3(256), 0, stream>>>(
        num, batch1, N1, batch2, N2, fW1, fb1, fW2, fb2, fW3, fb3, (float*)d_out);
}

// Round 7
// 274.676 us; speedup vs baseline: 1.4982x; 1.4982x over previous
//
#include <hip/hip_runtime.h>

// ObjectMeanDirectAttention — Round 7: spill-free single-pass kernel.
// R6 post-mortem: WRITE 392MB/FETCH 920MB = scratch spill (VGPR capped at 64 by
// launch_bounds(512,4)). Fixes:
//  - __launch_bounds__(512,2) -> VGPR cap >=128.
//  - coefs packed bf16 (b1: 4xuint2, b2|W3 fused: 4xuint4) = 25 regs instead of 48.
//  - scatter tile written BEFORE the MFMA chain (unscaled bf16 xb frags) -> x frag regs
//    die immediately; scatter = ds_read_u16 * shfl(a). x read from HBM exactly once.

#define NGRAPHS 4096
constexpr int LDP = 68;    // f32 LDS stride, final MLP
constexpr int LDU = 132;   // f32 LDS stride, 128-wide u tile
constexpr int LDXS = 72;   // bf16 LDS stride, scatter tile (144B rows: 16B-aligned, 2-way banks)

typedef short bf16x8 __attribute__((ext_vector_type(8)));
typedef float f32x4 __attribute__((ext_vector_type(4)));

union BF8 { bf16x8 v; unsigned u[4]; };

__device__ __forceinline__ unsigned short f2bf(float f) {
    unsigned u = __float_as_uint(f);
    return (unsigned short)((u + 0x7FFFu + ((u >> 16) & 1u)) >> 16);  // RNE
}

__device__ __forceinline__ unsigned cvt_pk_bf16(float lo, float hi) {
    unsigned r;
    asm("v_cvt_pk_bf16_f32 %0, %1, %2" : "=v"(r) : "v"(lo), "v"(hi));
    return r;
}

__device__ __forceinline__ float bflo(unsigned u) { return __uint_as_float(u << 16); }
__device__ __forceinline__ float bfhi(unsigned u) { return __uint_as_float(u & 0xffff0000u); }

__device__ __forceinline__ int lower_bound_i(const int* __restrict__ arr, int n, int v) {
    int lo = 0, hi = n;
    while (lo < hi) {
        int mid = (lo + hi) >> 1;
        if (arr[mid] < v) lo = mid + 1; else hi = mid;
    }
    return lo;
}

// one-shot prep:
//   w1p[r*64+k] = bf16(W1[k][pi(r)]), pi(16ct+4kb+reg) = 32*(ct>>1)+8kb+4*(ct&1)+reg
//   w2t[r*64+k] = bf16(W2[k][r])
//   coefpk[0..31]  = b1 packed pairs  [kb][ct][j]  (lo=b1[base+2j], hi=b1[base+2j+1])
//   coefpk[32..95] = (b2,W3) fused    [kb][ct][reg] (lo=b2[idx], hi=W3[idx])
__global__ __launch_bounds__(256)
void prep_kernel(const float* __restrict__ W1, const float* __restrict__ W2,
                 const float* __restrict__ b1, const float* __restrict__ b2,
                 const float* __restrict__ W3,
                 unsigned short* __restrict__ w1p, unsigned short* __restrict__ w2t,
                 unsigned* __restrict__ coefpk) {
    int e = blockIdx.x * 256 + threadIdx.x;     // 0..4095
    int r = e >> 6, k = e & 63;
    int ct = r >> 4, kb = (r >> 2) & 3, reg = r & 3;
    int pi = 32 * (ct >> 1) + 8 * kb + 4 * (ct & 1) + reg;
    w1p[e] = f2bf(W1[k * 64 + pi]);
    w2t[e] = f2bf(W2[k * 64 + r]);
    if (blockIdx.x == 0) {
        int t = threadIdx.x;
        if (t < 32) {
            int kb2 = t >> 3, ct2 = (t >> 1) & 3, j = t & 1;
            int base = 32 * (ct2 >> 1) + 4 * (ct2 & 1) + 8 * kb2 + 2 * j;
            coefpk[t] = ((unsigned)f2bf(b1[base + 1]) << 16) | (unsigned)f2bf(b1[base]);
        } else if (t < 96) {
            int e2 = t - 32;
            int kb2 = e2 >> 4, ct2 = (e2 >> 2) & 3, rg = e2 & 3;
            int idx = ct2 * 16 + 4 * kb2 + rg;
            coefpk[t] = ((unsigned)f2bf(W3[idx]) << 16) | (unsigned)f2bf(b2[idx]);
        }
    }
}

// ---------------- attention MLP + weighted scatter (both inputs, one launch) ----------------
__global__ __launch_bounds__(512, 2)
void attn_scatter_mfma(const float* __restrict__ x1, const int* __restrict__ batch1, int N1, int nblk1,
                       const float* __restrict__ x2, const int* __restrict__ batch2, int N2,
                       const unsigned short* __restrict__ w1p, const unsigned short* __restrict__ w2t,
                       const unsigned* __restrict__ coefpk, const float* __restrict__ b3,
                       float* __restrict__ num) {
    __shared__ alignas(16) unsigned short Xs[8][16 * LDXS];   // per-wave bf16 scatter tile

    const float* x; const int* batch; int N, col_off, blk;
    if ((int)blockIdx.x < nblk1) { x = x1; batch = batch1; N = N1; col_off = 0;  blk = blockIdx.x; }
    else                         { x = x2; batch = batch2; N = N2; col_off = 64; blk = blockIdx.x - nblk1; }

    const int t = threadIdx.x;
    const int w = t >> 6, l = t & 63;
    const int jj = l & 15, kb = l >> 4;
    const int base = blk * 512 + w * 64;          // this wave's 64 nodes
    if (base >= N) return;                        // dead tail wave

    // ---- packed coefficients (25 VGPRs total) ----
    const uint2* b1p = (const uint2*)coefpk;          // [kb*4+ct]
    const uint4* bwp = (const uint4*)(coefpk + 32);   // [kb*4+ct]
    uint2 b1c[4]; uint4 bwc[4];
#pragma unroll
    for (int ct = 0; ct < 4; ct++) {
        b1c[ct] = b1p[kb * 4 + ct];
        bwc[ct] = bwp[kb * 4 + ct];
    }
    const float b3v = b3[0];

    // ---- weight fragments (64 VGPRs, L1-resident loads) ----
    bf16x8 w1f[8], w2f[8];
#pragma unroll
    for (int ct = 0; ct < 4; ct++) {
        const int wrow = (ct * 16 + jj) * 64 + kb * 8;
        w1f[2 * ct]     = *(const bf16x8*)&w1p[wrow];
        w1f[2 * ct + 1] = *(const bf16x8*)&w1p[wrow + 32];
        w2f[2 * ct]     = *(const bf16x8*)&w2t[wrow];
        w2f[2 * ct + 1] = *(const bf16x8*)&w2t[wrow + 32];
    }

    unsigned short* Xw = Xs[w];
    float accv = 0.f;
    int gcur = -1;

#pragma unroll
    for (int q = 0; q < 4; ++q) {
        const int nbase = base + q * 16;
        const int row = nbase + jj;
        // x fragment: lane (jj,kb) holds node jj's feats kb*8..+7 and 32+kb*8..+7
        float4 v0 = make_float4(0.f, 0.f, 0.f, 0.f), v1 = v0, v2 = v0, v3 = v0;
        if (row < N) {
            const float* xr = x + (size_t)row * 64;
            v0 = *(const float4*)&xr[kb * 8];
            v1 = *(const float4*)&xr[kb * 8 + 4];
            v2 = *(const float4*)&xr[32 + kb * 8];
            v3 = *(const float4*)&xr[32 + kb * 8 + 4];
        }
        const int gb = batch[row < N ? row : (N - 1)];

        BF8 xb0, xb1;
        xb0.u[0] = cvt_pk_bf16(v0.x, v0.y); xb0.u[1] = cvt_pk_bf16(v0.z, v0.w);
        xb0.u[2] = cvt_pk_bf16(v1.x, v1.y); xb0.u[3] = cvt_pk_bf16(v1.z, v1.w);
        xb1.u[0] = cvt_pk_bf16(v2.x, v2.y); xb1.u[1] = cvt_pk_bf16(v2.z, v2.w);
        xb1.u[2] = cvt_pk_bf16(v3.x, v3.y); xb1.u[3] = cvt_pk_bf16(v3.z, v3.w);

        // stash unscaled bf16 tile NOW (frees v0..v3; per-wave DS ops are in-order)
        *(bf16x8*)&Xw[jj * LDXS + kb * 8]      = xb0.v;
        *(bf16x8*)&Xw[jj * LDXS + 32 + kb * 8] = xb1.v;

        // layer 1 (swapped): lane holds H1pre[node jj][pi(ct,kb,reg)]; bias from packed b1
        unsigned ph[8];
#pragma unroll
        for (int ct = 0; ct < 4; ++ct) {
            f32x4 acc = { bflo(b1c[ct].x), bfhi(b1c[ct].x), bflo(b1c[ct].y), bfhi(b1c[ct].y) };
            acc = __builtin_amdgcn_mfma_f32_16x16x32_bf16(w1f[2 * ct],     xb0.v, acc, 0, 0, 0);
            acc = __builtin_amdgcn_mfma_f32_16x16x32_bf16(w1f[2 * ct + 1], xb1.v, acc, 0, 0, 0);
            ph[2 * ct]     = cvt_pk_bf16(fmaxf(acc[0], 0.f), fmaxf(acc[1], 0.f));
            ph[2 * ct + 1] = cvt_pk_bf16(fmaxf(acc[2], 0.f), fmaxf(acc[3], 0.f));
        }
        BF8 bh0, bh1;
        bh0.u[0] = ph[0]; bh0.u[1] = ph[1]; bh0.u[2] = ph[2]; bh0.u[3] = ph[3];
        bh1.u[0] = ph[4]; bh1.u[1] = ph[5]; bh1.u[2] = ph[6]; bh1.u[3] = ph[7];

        // layer 2+3 (swapped): p = sum relu(h2pre + b2)*W3, coefs unpacked from bwc
        float p = 0.f;
#pragma unroll
        for (int ct = 0; ct < 4; ++ct) {
            f32x4 acc = { 0.f, 0.f, 0.f, 0.f };
            acc = __builtin_amdgcn_mfma_f32_16x16x32_bf16(w2f[2 * ct],     bh0.v, acc, 0, 0, 0);
            acc = __builtin_amdgcn_mfma_f32_16x16x32_bf16(w2f[2 * ct + 1], bh1.v, acc, 0, 0, 0);
            p += fmaxf(acc[0] + bflo(bwc[ct].x), 0.f) * bfhi(bwc[ct].x)
               + fmaxf(acc[1] + bflo(bwc[ct].y), 0.f) * bfhi(bwc[ct].y)
               + fmaxf(acc[2] + bflo(bwc[ct].z), 0.f) * bfhi(bwc[ct].z)
               + fmaxf(acc[3] + bflo(bwc[ct].w), 0.f) * bfhi(bwc[ct].w);
        }
        // reduce 4 kb partials -> every lane holds a[its node jj]
        p += __shfl_xor(p, 16);
        p += __shfl_xor(p, 32);
        const float a = p + b3v;

        // scatter: num[g][col_off+l] += x[n][l]*a[n]; reads the bf16 tile, flushes on boundary
        if (gcur < 0) gcur = __shfl(gb, 0);
#pragma unroll
        for (int i = 0; i < 16; ++i) {
            const int n = nbase + i;
            if (n < N) {                                   // wave-uniform
                const int g = __shfl(gb, i);
                const float ai = __shfl(a, i);
                if (g != gcur) {
                    atomicAdd(&num[(size_t)gcur * 128 + col_off + l], accv);
                    accv = 0.f;
                    gcur = g;
                }
                accv += __uint_as_float(((unsigned)Xw[i * LDXS + l]) << 16) * ai;
            }
        }
    }
    atomicAdd(&num[(size_t)gcur * 128 + col_off + l], accv);
}

// ---------------- final MLP (f32, unchanged: negligible time) ----------------
template<int K, int LDAa, int LDBb>
__device__ __forceinline__ void tile_gemm(const float* __restrict__ As,
                                          const float* __restrict__ Bs,
                                          float acc[4][4], int n0, int j0) {
#pragma unroll 4
    for (int k0 = 0; k0 < K; k0 += 4) {
        float4 a[4], wv[4];
#pragma unroll
        for (int i = 0; i < 4; i++) a[i] = *(const float4*)&As[(n0 + i) * LDAa + k0];
#pragma unroll
        for (int kk = 0; kk < 4; kk++) wv[kk] = *(const float4*)&Bs[(k0 + kk) * LDBb + j0];
#pragma unroll
        for (int i = 0; i < 4; i++) {
            const float av0 = a[i].x, av1 = a[i].y, av2 = a[i].z, av3 = a[i].w;
            acc[i][0] += av0 * wv[0].x; acc[i][1] += av0 * wv[0].y; acc[i][2] += av0 * wv[0].z; acc[i][3] += av0 * wv[0].w;
            acc[i][0] += av1 * wv[1].x; acc[i][1] += av1 * wv[1].y; acc[i][2] += av1 * wv[1].z; acc[i][3] += av1 * wv[1].w;
            acc[i][0] += av2 * wv[2].x; acc[i][1] += av2 * wv[2].y; acc[i][2] += av2 * wv[2].z; acc[i][3] += av2 * wv[2].w;
            acc[i][0] += av3 * wv[3].x; acc[i][1] += av3 * wv[3].y; acc[i][2] += av3 * wv[3].z; acc[i][3] += av3 * wv[3].w;
        }
    }
}

__global__ __launch_bounds__(256)
void final_mlp_kernel(const float* __restrict__ num,
                      const int* __restrict__ batch1, int N1,
                      const int* __restrict__ batch2, int N2,
                      const float* __restrict__ W1, const float* __restrict__ b1,  // [128][64]
                      const float* __restrict__ W2, const float* __restrict__ b2,  // [64][64]
                      const float* __restrict__ W3, const float* __restrict__ b3,  // [64][64]
                      float* __restrict__ out) {
    __shared__ float Us[64 * LDU];
    __shared__ float W1s[128 * LDP];
    __shared__ float W2s[64 * LDP];
    __shared__ float W3s[64 * LDP];
    __shared__ float Hs[64 * LDP];
    __shared__ float inv1[64], inv2[64];

    const int t = threadIdx.x;
    const int rowbase = blockIdx.x * 64;

    if (t < 64) {
        int g = rowbase + t;
        int c = lower_bound_i(batch1, N1, g + 1) - lower_bound_i(batch1, N1, g);
        inv1[t] = 1.0f / (float)max(c, 1);
    } else if (t < 128) {
        int g = rowbase + (t - 64);
        int c = lower_bound_i(batch2, N2, g + 1) - lower_bound_i(batch2, N2, g);
        inv2[t - 64] = 1.0f / (float)max(c, 1);
    }

    {
        const float4* W1v = (const float4*)W1;
#pragma unroll
        for (int r = 0; r < 8; r++) {
            int e4 = t + 256 * r;
            int e = e4 * 4;
            int k = e / 64, j = e % 64;
            *(float4*)&W1s[k * LDP + j] = W1v[e4];
        }
        const float4* W2v = (const float4*)W2;
        const float4* W3v = (const float4*)W3;
#pragma unroll
        for (int r = 0; r < 4; r++) {
            int e4 = t + 256 * r;
            int e = e4 * 4;
            int k = e / 64, j = e % 64;
            *(float4*)&W2s[k * LDP + j] = W2v[e4];
            *(float4*)&W3s[k * LDP + j] = W3v[e4];
        }
    }
    __syncthreads();

    {
        const float4* nv = (const float4*)(num + (size_t)rowbase * 128);
#pragma unroll
        for (int r = 0; r < 8; r++) {
            int e4 = t + 256 * r;
            int e = e4 * 4;
            int row = e / 128, col = e % 128;
            float4 v = nv[e4];
            float s = (col < 64) ? inv1[row] : inv2[row];
            v.x *= s; v.y *= s; v.z *= s; v.w *= s;
            *(float4*)&Us[row * LDU + col] = v;
        }
    }
    __syncthreads();

    const int fg = t & 15, ng = t >> 4;
    const int j0 = fg * 4, n0 = ng * 4;

    float acc[4][4];
#pragma unroll
    for (int i = 0; i < 4; i++) { acc[i][0] = 0.f; acc[i][1] = 0.f; acc[i][2] = 0.f; acc[i][3] = 0.f; }
    tile_gemm<128, LDU, LDP>(Us, W1s, acc, n0, j0);
    {
        float4 bb = *(const float4*)&b1[j0];
#pragma unroll
        for (int i = 0; i < 4; i++) {
            float4 hv;
            hv.x = fmaxf(acc[i][0] + bb.x, 0.f);
            hv.y = fmaxf(acc[i][1] + bb.y, 0.f);
            hv.z = fmaxf(acc[i][2] + bb.z, 0.f);
            hv.w = fmaxf(acc[i][3] + bb.w, 0.f);
            *(float4*)&Hs[(n0 + i) * LDP + j0] = hv;
        }
    }
    __syncthreads();

#pragma unroll
    for (int i = 0; i < 4; i++) { acc[i][0] = 0.f; acc[i][1] = 0.f; acc[i][2] = 0.f; acc[i][3] = 0.f; }
    tile_gemm<64, LDP, LDP>(Hs, W2s, acc, n0, j0);
    {
        float4 bb = *(const float4*)&b2[j0];
#pragma unroll
        for (int i = 0; i < 4; i++) {
            float4 hv;
            hv.x = fmaxf(acc[i][0] + bb.x, 0.f);
            hv.y = fmaxf(acc[i][1] + bb.y, 0.f);
            hv.z = fmaxf(acc[i][2] + bb.z, 0.f);
            hv.w = fmaxf(acc[i][3] + bb.w, 0.f);
            *(float4*)&Us[(n0 + i) * LDU + j0] = hv;
        }
    }
    __syncthreads();

#pragma unroll
    for (int i = 0; i < 4; i++) { acc[i][0] = 0.f; acc[i][1] = 0.f; acc[i][2] = 0.f; acc[i][3] = 0.f; }
    tile_gemm<64, LDU, LDP>(Us, W3s, acc, n0, j0);
    {
        float4 bb = *(const float4*)&b3[j0];
#pragma unroll
        for (int i = 0; i < 4; i++) {
            float4 ov;
            ov.x = acc[i][0] + bb.x;
            ov.y = acc[i][1] + bb.y;
            ov.z = acc[i][2] + bb.z;
            ov.w = acc[i][3] + bb.w;
            *(float4*)&out[(size_t)(rowbase + n0 + i) * 64 + j0] = ov;
        }
    }
}

extern "C" void kernel_launch(void* const* d_in, const int* in_sizes, int n_in,
                              void* d_out, int out_size, void* d_ws, size_t ws_size,
                              hipStream_t stream) {
    const float* x1     = (const float*)d_in[0];
    const int*   batch1 = (const int*)d_in[1];
    const float* x2     = (const float*)d_in[2];
    const int*   batch2 = (const int*)d_in[3];
    const float* aW1    = (const float*)d_in[4];
    const float* ab1    = (const float*)d_in[5];
    const float* aW2    = (const float*)d_in[6];
    const float* ab2    = (const float*)d_in[7];
    const float* aW3    = (const float*)d_in[8];
    const float* ab3    = (const float*)d_in[9];
    const float* fW1    = (const float*)d_in[10];
    const float* fb1    = (const float*)d_in[11];
    const float* fW2    = (const float*)d_in[12];
    const float* fb2    = (const float*)d_in[13];
    const float* fW3    = (const float*)d_in[14];
    const float* fb3    = (const float*)d_in[15];

    const int N1 = in_sizes[0] / 64;
    const int N2 = in_sizes[2] / 64;

    // ws layout: [w1p 8KB][w2t 8KB][coefpk 1KB][num f32 4096x128 = 2MB]
    unsigned short* w1p = (unsigned short*)d_ws;
    unsigned short* w2t = w1p + 64 * 64;
    unsigned* coefpk = (unsigned*)((char*)d_ws + 16384);
    float* num = (float*)((char*)d_ws + 17408);

    prep_kernel<<<dim3(16), dim3(256), 0, stream>>>(aW1, aW2, ab1, ab2, aW3, w1p, w2t, coefpk);
    hipMemsetAsync(num, 0, (size_t)NGRAPHS * 128 * sizeof(float), stream);

    const int nblk1 = (N1 + 511) / 512;
    const int nblk2 = (N2 + 511) / 512;
    attn_scatter_mfma<<<dim3(nblk1 + nblk2), dim3(512), 0, stream>>>(
        x1, batch1, N1, nblk1, x2, batch2, N2,
        w1p, w2t, coefpk, ab3, num);
    final_mlp_kernel<<<dim3(NGRAPHS / 64), dim3(256), 0, stream>>>(
        num, batch1, N1, batch2, N2, fW1, fb1, fW2, fb2, fW3, fb3, (float*)d_out);
}

// Round 8
// 272.479 us; speedup vs baseline: 1.5102x; 1.0081x over previous
//
#include <hip/hip_runtime.h>

// ObjectMeanDirectAttention — Round 8: R7 + pipelining.
// - 1-deep x prefetch across q (8 KB/wave in flight, counted vmcnt)
// - one batch load per wave (shfl-distributed), scatter via 4 partial accumulators
//   + uniform-graph fast path (no per-i boundary logic in the common case)
// - w2 fragments loaded per-q (L1-hot) to keep VGPR <= 128 at (512,2): no spill

#define NGRAPHS 4096
constexpr int LDP = 68;    // f32 LDS stride, final MLP
constexpr int LDU = 132;   // f32 LDS stride, 128-wide u tile
constexpr int LDXS = 72;   // bf16 LDS stride, scatter tile (144B rows)

typedef short bf16x8 __attribute__((ext_vector_type(8)));
typedef float f32x4 __attribute__((ext_vector_type(4)));

union BF8 { bf16x8 v; unsigned u[4]; };

__device__ __forceinline__ unsigned short f2bf(float f) {
    unsigned u = __float_as_uint(f);
    return (unsigned short)((u + 0x7FFFu + ((u >> 16) & 1u)) >> 16);  // RNE
}

__device__ __forceinline__ unsigned cvt_pk_bf16(float lo, float hi) {
    unsigned r;
    asm("v_cvt_pk_bf16_f32 %0, %1, %2" : "=v"(r) : "v"(lo), "v"(hi));
    return r;
}

__device__ __forceinline__ float bflo(unsigned u) { return __uint_as_float(u << 16); }
__device__ __forceinline__ float bfhi(unsigned u) { return __uint_as_float(u & 0xffff0000u); }

__device__ __forceinline__ int lower_bound_i(const int* __restrict__ arr, int n, int v) {
    int lo = 0, hi = n;
    while (lo < hi) {
        int mid = (lo + hi) >> 1;
        if (arr[mid] < v) lo = mid + 1; else hi = mid;
    }
    return lo;
}

// one-shot prep (unchanged from R7)
__global__ __launch_bounds__(256)
void prep_kernel(const float* __restrict__ W1, const float* __restrict__ W2,
                 const float* __restrict__ b1, const float* __restrict__ b2,
                 const float* __restrict__ W3,
                 unsigned short* __restrict__ w1p, unsigned short* __restrict__ w2t,
                 unsigned* __restrict__ coefpk) {
    int e = blockIdx.x * 256 + threadIdx.x;     // 0..4095
    int r = e >> 6, k = e & 63;
    int ct = r >> 4, kb = (r >> 2) & 3, reg = r & 3;
    int pi = 32 * (ct >> 1) + 8 * kb + 4 * (ct & 1) + reg;
    w1p[e] = f2bf(W1[k * 64 + pi]);
    w2t[e] = f2bf(W2[k * 64 + r]);
    if (blockIdx.x == 0) {
        int t = threadIdx.x;
        if (t < 32) {
            int kb2 = t >> 3, ct2 = (t >> 1) & 3, j = t & 1;
            int base = 32 * (ct2 >> 1) + 4 * (ct2 & 1) + 8 * kb2 + 2 * j;
            coefpk[t] = ((unsigned)f2bf(b1[base + 1]) << 16) | (unsigned)f2bf(b1[base]);
        } else if (t < 96) {
            int e2 = t - 32;
            int kb2 = e2 >> 4, ct2 = (e2 >> 2) & 3, rg = e2 & 3;
            int idx = ct2 * 16 + 4 * kb2 + rg;
            coefpk[t] = ((unsigned)f2bf(W3[idx]) << 16) | (unsigned)f2bf(b2[idx]);
        }
    }
}

// ---------------- attention MLP + weighted scatter ----------------
__global__ __launch_bounds__(512, 2)
void attn_scatter_mfma(const float* __restrict__ x1, const int* __restrict__ batch1, int N1, int nblk1,
                       const float* __restrict__ x2, const int* __restrict__ batch2, int N2,
                       const unsigned short* __restrict__ w1p, const unsigned short* __restrict__ w2t,
                       const unsigned* __restrict__ coefpk, const float* __restrict__ b3,
                       float* __restrict__ num) {
    __shared__ alignas(16) unsigned short Xs[8][16 * LDXS];   // per-wave bf16 scatter tile

    const float* x; const int* batch; int N, col_off, blk;
    if ((int)blockIdx.x < nblk1) { x = x1; batch = batch1; N = N1; col_off = 0;  blk = blockIdx.x; }
    else                         { x = x2; batch = batch2; N = N2; col_off = 64; blk = blockIdx.x - nblk1; }

    const int t = threadIdx.x;
    const int w = t >> 6, l = t & 63;
    const int jj = l & 15, kb = l >> 4;
    const int base = blk * 512 + w * 64;          // this wave's 64 nodes
    if (base >= N) return;                        // dead tail wave

    // ---- packed coefficients ----
    const uint2* b1p = (const uint2*)coefpk;          // [kb*4+ct]
    const uint4* bwp = (const uint4*)(coefpk + 32);   // [kb*4+ct]
    uint2 b1c[4]; uint4 bwc[4];
#pragma unroll
    for (int ct = 0; ct < 4; ct++) {
        b1c[ct] = b1p[kb * 4 + ct];
        bwc[ct] = bwp[kb * 4 + ct];
    }
    const float b3v = b3[0];

    // ---- w1 fragments resident (32 VGPR); w2 loaded per-q ----
    bf16x8 w1f[8];
#pragma unroll
    for (int ct = 0; ct < 4; ct++) {
        const int wrow = (ct * 16 + jj) * 64 + kb * 8;
        w1f[2 * ct]     = *(const bf16x8*)&w1p[wrow];
        w1f[2 * ct + 1] = *(const bf16x8*)&w1p[wrow + 32];
    }

    // ---- all 64 batch ids in one load (lane l -> batch[base+l]) ----
    const int gball = batch[min(base + l, N - 1)];

    unsigned short* Xw = Xs[w];
    float ac0 = 0.f, ac1 = 0.f, ac2 = 0.f, ac3 = 0.f;
    int gcur = __shfl(gball, 0);

    // ---- prologue: q=0 x loads ----
    float4 c0, c1, c2, c3;
    {
        const int row = base + jj;
        c0 = c1 = c2 = c3 = make_float4(0.f, 0.f, 0.f, 0.f);
        if (row < N) {
            const float* xr = x + (size_t)row * 64;
            c0 = *(const float4*)&xr[kb * 8];
            c1 = *(const float4*)&xr[kb * 8 + 4];
            c2 = *(const float4*)&xr[32 + kb * 8];
            c3 = *(const float4*)&xr[32 + kb * 8 + 4];
        }
    }

#pragma unroll
    for (int q = 0; q < 4; ++q) {
        const int nbase = base + q * 16;

        // ---- issue q+1 loads FIRST (independent; keeps 8 KB/wave in flight) ----
        float4 n0, n1, n2, n3;
        n0 = n1 = n2 = n3 = make_float4(0.f, 0.f, 0.f, 0.f);
        if (q < 3) {
            const int rown = nbase + 16 + jj;
            if (rown < N) {
                const float* xr = x + (size_t)rown * 64;
                n0 = *(const float4*)&xr[kb * 8];
                n1 = *(const float4*)&xr[kb * 8 + 4];
                n2 = *(const float4*)&xr[32 + kb * 8];
                n3 = *(const float4*)&xr[32 + kb * 8 + 4];
            }
        }

        // ---- convert current q, stash scatter tile ----
        BF8 xb0, xb1;
        xb0.u[0] = cvt_pk_bf16(c0.x, c0.y); xb0.u[1] = cvt_pk_bf16(c0.z, c0.w);
        xb0.u[2] = cvt_pk_bf16(c1.x, c1.y); xb0.u[3] = cvt_pk_bf16(c1.z, c1.w);
        xb1.u[0] = cvt_pk_bf16(c2.x, c2.y); xb1.u[1] = cvt_pk_bf16(c2.z, c2.w);
        xb1.u[2] = cvt_pk_bf16(c3.x, c3.y); xb1.u[3] = cvt_pk_bf16(c3.z, c3.w);
        *(bf16x8*)&Xw[jj * LDXS + kb * 8]      = xb0.v;
        *(bf16x8*)&Xw[jj * LDXS + 32 + kb * 8] = xb1.v;

        // ---- w2 fragments for this q (L1-hot; latency covered by L1 MFMA chain) ----
        bf16x8 w2f[8];
#pragma unroll
        for (int ct = 0; ct < 4; ct++) {
            const int wrow = (ct * 16 + jj) * 64 + kb * 8;
            w2f[2 * ct]     = *(const bf16x8*)&w2t[wrow];
            w2f[2 * ct + 1] = *(const bf16x8*)&w2t[wrow + 32];
        }

        // ---- layer 1 (swapped): lane holds H1pre[node jj][pi(ct,kb,reg)] ----
        unsigned ph[8];
#pragma unroll
        for (int ct = 0; ct < 4; ++ct) {
            f32x4 acc = { bflo(b1c[ct].x), bfhi(b1c[ct].x), bflo(b1c[ct].y), bfhi(b1c[ct].y) };
            acc = __builtin_amdgcn_mfma_f32_16x16x32_bf16(w1f[2 * ct],     xb0.v, acc, 0, 0, 0);
            acc = __builtin_amdgcn_mfma_f32_16x16x32_bf16(w1f[2 * ct + 1], xb1.v, acc, 0, 0, 0);
            ph[2 * ct]     = cvt_pk_bf16(fmaxf(acc[0], 0.f), fmaxf(acc[1], 0.f));
            ph[2 * ct + 1] = cvt_pk_bf16(fmaxf(acc[2], 0.f), fmaxf(acc[3], 0.f));
        }
        BF8 bh0, bh1;
        bh0.u[0] = ph[0]; bh0.u[1] = ph[1]; bh0.u[2] = ph[2]; bh0.u[3] = ph[3];
        bh1.u[0] = ph[4]; bh1.u[1] = ph[5]; bh1.u[2] = ph[6]; bh1.u[3] = ph[7];

        // ---- layer 2+3 (swapped) ----
        float p = 0.f;
#pragma unroll
        for (int ct = 0; ct < 4; ++ct) {
            f32x4 acc = { 0.f, 0.f, 0.f, 0.f };
            acc = __builtin_amdgcn_mfma_f32_16x16x32_bf16(w2f[2 * ct],     bh0.v, acc, 0, 0, 0);
            acc = __builtin_amdgcn_mfma_f32_16x16x32_bf16(w2f[2 * ct + 1], bh1.v, acc, 0, 0, 0);
            p += fmaxf(acc[0] + bflo(bwc[ct].x), 0.f) * bfhi(bwc[ct].x)
               + fmaxf(acc[1] + bflo(bwc[ct].y), 0.f) * bfhi(bwc[ct].y)
               + fmaxf(acc[2] + bflo(bwc[ct].z), 0.f) * bfhi(bwc[ct].z)
               + fmaxf(acc[3] + bflo(bwc[ct].w), 0.f) * bfhi(bwc[ct].w);
        }
        p += __shfl_xor(p, 16);
        p += __shfl_xor(p, 32);
        const float a = p + b3v;     // a[node jj], all kb copies

        // ---- scatter: 4 partial accumulators; uniform fast path ----
        const int lim = min(16, N - nbase);
        const int gfirst = __shfl(gball, q * 16);
        const int glast  = __shfl(gball, q * 16 + 15);
        if (lim == 16 && gfirst == glast && gfirst == gcur) {
#pragma unroll
            for (int i = 0; i < 16; i += 4) {
                ac0 += __uint_as_float(((unsigned)Xw[(i + 0) * LDXS + l]) << 16) * __shfl(a, i + 0);
                ac1 += __uint_as_float(((unsigned)Xw[(i + 1) * LDXS + l]) << 16) * __shfl(a, i + 1);
                ac2 += __uint_as_float(((unsigned)Xw[(i + 2) * LDXS + l]) << 16) * __shfl(a, i + 2);
                ac3 += __uint_as_float(((unsigned)Xw[(i + 3) * LDXS + l]) << 16) * __shfl(a, i + 3);
            }
        } else {
#pragma unroll
            for (int i = 0; i < 16; ++i) {
                if (i < lim) {                              // wave-uniform
                    const int g = __shfl(gball, q * 16 + i);
                    const float ai = __shfl(a, i);
                    if (g != gcur) {
                        const float s = (ac0 + ac1) + (ac2 + ac3);
                        atomicAdd(&num[(size_t)gcur * 128 + col_off + l], s);
                        ac0 = ac1 = ac2 = ac3 = 0.f;
                        gcur = g;
                    }
                    ac0 += __uint_as_float(((unsigned)Xw[i * LDXS + l]) << 16) * ai;
                }
            }
        }

        // rotate prefetch buffers
        c0 = n0; c1 = n1; c2 = n2; c3 = n3;
    }
    {
        const float s = (ac0 + ac1) + (ac2 + ac3);
        atomicAdd(&num[(size_t)gcur * 128 + col_off + l], s);
    }
}

// ---------------- final MLP (f32, unchanged: negligible time) ----------------
template<int K, int LDAa, int LDBb>
__device__ __forceinline__ void tile_gemm(const float* __restrict__ As,
                                          const float* __restrict__ Bs,
                                          float acc[4][4], int n0, int j0) {
#pragma unroll 4
    for (int k0 = 0; k0 < K; k0 += 4) {
        float4 a[4], wv[4];
#pragma unroll
        for (int i = 0; i < 4; i++) a[i] = *(const float4*)&As[(n0 + i) * LDAa + k0];
#pragma unroll
        for (int kk = 0; kk < 4; kk++) wv[kk] = *(const float4*)&Bs[(k0 + kk) * LDBb + j0];
#pragma unroll
        for (int i = 0; i < 4; i++) {
            const float av0 = a[i].x, av1 = a[i].y, av2 = a[i].z, av3 = a[i].w;
            acc[i][0] += av0 * wv[0].x; acc[i][1] += av0 * wv[0].y; acc[i][2] += av0 * wv[0].z; acc[i][3] += av0 * wv[0].w;
            acc[i][0] += av1 * wv[1].x; acc[i][1] += av1 * wv[1].y; acc[i][2] += av1 * wv[1].z; acc[i][3] += av1 * wv[1].w;
            acc[i][0] += av2 * wv[2].x; acc[i][1] += av2 * wv[2].y; acc[i][2] += av2 * wv[2].z; acc[i][3] += av2 * wv[2].w;
            acc[i][0] += av3 * wv[3].x; acc[i][1] += av3 * wv[3].y; acc[i][2] += av3 * wv[3].z; acc[i][3] += av3 * wv[3].w;
        }
    }
}

__global__ __launch_bounds__(256)
void final_mlp_kernel(const float* __restrict__ num,
                      const int* __restrict__ batch1, int N1,
                      const int* __restrict__ batch2, int N2,
                      const float* __restrict__ W1, const float* __restrict__ b1,  // [128][64]
                      const float* __restrict__ W2, const float* __restrict__ b2,  // [64][64]
                      const float* __restrict__ W3, const float* __restrict__ b3,  // [64][64]
                      float* __restrict__ out) {
    __shared__ float Us[64 * LDU];
    __shared__ float W1s[128 * LDP];
    __shared__ float W2s[64 * LDP];
    __shared__ float W3s[64 * LDP];
    __shared__ float Hs[64 * LDP];
    __shared__ float inv1[64], inv2[64];

    const int t = threadIdx.x;
    const int rowbase = blockIdx.x * 64;

    if (t < 64) {
        int g = rowbase + t;
        int c = lower_bound_i(batch1, N1, g + 1) - lower_bound_i(batch1, N1, g);
        inv1[t] = 1.0f / (float)max(c, 1);
    } else if (t < 128) {
        int g = rowbase + (t - 64);
        int c = lower_bound_i(batch2, N2, g + 1) - lower_bound_i(batch2, N2, g);
        inv2[t - 64] = 1.0f / (float)max(c, 1);
    }

    {
        const float4* W1v = (const float4*)W1;
#pragma unroll
        for (int r = 0; r < 8; r++) {
            int e4 = t + 256 * r;
            int e = e4 * 4;
            int k = e / 64, j = e % 64;
            *(float4*)&W1s[k * LDP + j] = W1v[e4];
        }
        const float4* W2v = (const float4*)W2;
        const float4* W3v = (const float4*)W3;
#pragma unroll
        for (int r = 0; r < 4; r++) {
            int e4 = t + 256 * r;
            int e = e4 * 4;
            int k = e / 64, j = e % 64;
            *(float4*)&W2s[k * LDP + j] = W2v[e4];
            *(float4*)&W3s[k * LDP + j] = W3v[e4];
        }
    }
    __syncthreads();

    {
        const float4* nv = (const float4*)(num + (size_t)rowbase * 128);
#pragma unroll
        for (int r = 0; r < 8; r++) {
            int e4 = t + 256 * r;
            int e = e4 * 4;
            int row = e / 128, col = e % 128;
            float4 v = nv[e4];
            float s = (col < 64) ? inv1[row] : inv2[row];
            v.x *= s; v.y *= s; v.z *= s; v.w *= s;
            *(float4*)&Us[row * LDU + col] = v;
        }
    }
    __syncthreads();

    const int fg = t & 15, ng = t >> 4;
    const int j0 = fg * 4, n0 = ng * 4;

    float acc[4][4];
#pragma unroll
    for (int i = 0; i < 4; i++) { acc[i][0] = 0.f; acc[i][1] = 0.f; acc[i][2] = 0.f; acc[i][3] = 0.f; }
    tile_gemm<128, LDU, LDP>(Us, W1s, acc, n0, j0);
    {
        float4 bb = *(const float4*)&b1[j0];
#pragma unroll
        for (int i = 0; i < 4; i++) {
            float4 hv;
            hv.x = fmaxf(acc[i][0] + bb.x, 0.f);
            hv.y = fmaxf(acc[i][1] + bb.y, 0.f);
            hv.z = fmaxf(acc[i][2] + bb.z, 0.f);
            hv.w = fmaxf(acc[i][3] + bb.w, 0.f);
            *(float4*)&Hs[(n0 + i) * LDP + j0] = hv;
        }
    }
    __syncthreads();

#pragma unroll
    for (int i = 0; i < 4; i++) { acc[i][0] = 0.f; acc[i][1] = 0.f; acc[i][2] = 0.f; acc[i][3] = 0.f; }
    tile_gemm<64, LDP, LDP>(Hs, W2s, acc, n0, j0);
    {
        float4 bb = *(const float4*)&b2[j0];
#pragma unroll
        for (int i = 0; i < 4; i++) {
            float4 hv;
            hv.x = fmaxf(acc[i][0] + bb.x, 0.f);
            hv.y = fmaxf(acc[i][1] + bb.y, 0.f);
            hv.z = fmaxf(acc[i][2] + bb.z, 0.f);
            hv.w = fmaxf(acc[i][3] + bb.w, 0.f);
            *(float4*)&Us[(n0 + i) * LDU + j0] = hv;
        }
    }
    __syncthreads();

#pragma unroll
    for (int i = 0; i < 4; i++) { acc[i][0] = 0.f; acc[i][1] = 0.f; acc[i][2] = 0.f; acc[i][3] = 0.f; }
    tile_gemm<64, LDU, LDP>(Us, W3s, acc, n0, j0);
    {
        float4 bb = *(const float4*)&b3[j0];
#pragma unroll
        for (int i = 0; i < 4; i++) {
            float4 ov;
            ov.x = acc[i][0] + bb.x;
            ov.y = acc[i][1] + bb.y;
            ov.z = acc[i][2] + bb.z;
            ov.w = acc[i][3] + bb.w;
            *(float4*)&out[(size_t)(rowbase + n0 + i) * 64 + j0] = ov;
        }
    }
}

extern "C" void kernel_launch(void* const* d_in, const int* in_sizes, int n_in,
                              void* d_out, int out_size, void* d_ws, size_t ws_size,
                              hipStream_t stream) {
    const float* x1     = (const float*)d_in[0];
    const int*   batch1 = (const int*)d_in[1];
    const float* x2     = (const float*)d_in[2];
    const int*   batch2 = (const int*)d_in[3];
    const float* aW1    = (const float*)d_in[4];
    const float* ab1    = (const float*)d_in[5];
    const float* aW2    = (const float*)d_in[6];
    const float* ab2    = (const float*)d_in[7];
    const float* aW3    = (const float*)d_in[8];
    const float* ab3    = (const float*)d_in[9];
    const float* fW1    = (const float*)d_in[10];
    const float* fb1    = (const float*)d_in[11];
    const float* fW2    = (const float*)d_in[12];
    const float* fb2    = (const float*)d_in[13];
    const float* fW3    = (const float*)d_in[14];
    const float* fb3    = (const float*)d_in[15];

    const int N1 = in_sizes[0] / 64;
    const int N2 = in_sizes[2] / 64;

    // ws layout: [w1p 8KB][w2t 8KB][coefpk 1KB][num f32 4096x128 = 2MB]
    unsigned short* w1p = (unsigned short*)d_ws;
    unsigned short* w2t = w1p + 64 * 64;
    unsigned* coefpk = (unsigned*)((char*)d_ws + 16384);
    float* num = (float*)((char*)d_ws + 17408);

    prep_kernel<<<dim3(16), dim3(256), 0, stream>>>(aW1, aW2, ab1, ab2, aW3, w1p, w2t, coefpk);
    hipMemsetAsync(num, 0, (size_t)NGRAPHS * 128 * sizeof(float), stream);

    const int nblk1 = (N1 + 511) / 512;
    const int nblk2 = (N2 + 511) / 512;
    attn_scatter_mfma<<<dim3(nblk1 + nblk2), dim3(512), 0, stream>>>(
        x1, batch1, N1, nblk1, x2, batch2, N2,
        w1p, w2t, coefpk, ab3, num);
    final_mlp_kernel<<<dim3(NGRAPHS / 64), dim3(256), 0, stream>>>(
        num, batch1, N1, batch2, N2, fW1, fb1, fW2, fb2, fW3, fb3, (float*)d_out);
}